// Round 1
// baseline (305.962 us; speedup 1.0000x reference)
//
#include <hip/hip_runtime.h>

#define K_DIM 8192
#define M_REAL 2000
#define N_REAL 2000
#define M_PAD 2048
#define N_PAD 2048

#define BM 128
#define BN 128
#define BK 32

typedef __bf16 bf16x8 __attribute__((ext_vector_type(8)));
typedef float f32x4 __attribute__((ext_vector_type(4)));

__device__ __forceinline__ unsigned short f2bf(float f) {
    union { float f; unsigned u; } v; v.f = f;
    unsigned r = v.u + 0x7FFFu + ((v.u >> 16) & 1u);  // RNE; inputs are finite normals
    return (unsigned short)(r >> 16);
}

__device__ __forceinline__ void async16(const void* g, void* l) {
    __builtin_amdgcn_global_load_lds((__attribute__((address_space(1))) void*)(g),
                                     (__attribute__((address_space(3))) void*)(l),
                                     16, 0, 0);
}

// ---------------------------------------------------------------------------
// W [2000][8192] f32 -> Wb [2048][8192] bf16, pad rows zeroed.
// 8 elements/thread, fully coalesced.
__global__ __launch_bounds__(256) void conv_w_kernel(const float* __restrict__ W,
                                                     unsigned short* __restrict__ Wb) {
    long long t = (long long)blockIdx.x * 256 + threadIdx.x;
    long long e = t * 8;                 // element index in [0, 2048*8192)
    int m = (int)(e >> 13);
    ushort4 o0 = make_ushort4(0, 0, 0, 0), o1 = o0;
    if (m < M_REAL) {
        const float4* src = (const float4*)(W + e);
        float4 f0 = src[0], f1 = src[1];
        o0.x = f2bf(f0.x); o0.y = f2bf(f0.y); o0.z = f2bf(f0.z); o0.w = f2bf(f0.w);
        o1.x = f2bf(f1.x); o1.y = f2bf(f1.y); o1.z = f2bf(f1.z); o1.w = f2bf(f1.w);
    }
    *(ushort4*)(Wb + e) = o0;
    *(ushort4*)(Wb + e + 4) = o1;
}

// ---------------------------------------------------------------------------
// X [8192][2000] f32 -> XT [2048][8192] bf16, XT[n][k] = X[k][n], pad rows zeroed.
// 64x64 tile transpose through LDS (+1-pad to kill bank conflicts).
__global__ __launch_bounds__(256) void conv_xt_kernel(const float* __restrict__ X,
                                                      unsigned short* __restrict__ XT) {
    __shared__ unsigned short tile[64][65];
    int k0 = blockIdx.x * 64;
    int n0 = blockIdx.y * 64;
    int tx = threadIdx.x & 63;   // n-offset on read, lane pos
    int ty = threadIdx.x >> 6;   // 0..3
    int n = n0 + tx;
#pragma unroll
    for (int it = 0; it < 16; ++it) {
        int k = k0 + ty + it * 4;
        float v = (n < N_REAL) ? X[(long long)k * N_REAL + n] : 0.0f;
        tile[ty + it * 4][tx] = f2bf(v);
    }
    __syncthreads();
    int kx = (threadIdx.x & 31) * 2;  // 0..62, pairs of k
    int ny = threadIdx.x >> 5;        // 0..7
#pragma unroll
    for (int it = 0; it < 8; ++it) {
        int nn = ny + it * 8;
        unsigned a = tile[kx][nn];
        unsigned b = tile[kx + 1][nn];
        *(unsigned*)(&XT[(long long)(n0 + nn) * K_DIM + k0 + kx]) = a | (b << 16);
    }
}

// ---------------------------------------------------------------------------
// GEMM: out[m][n] = sum_k Wb[m][k] * XT[n][k] + bias[n]
// 128x128 block tile, BK=32, 4 waves each computing 64x64 via 4x4 MFMA 16x16x32.
__global__ __launch_bounds__(256) void gemm_kernel(const unsigned short* __restrict__ Wb,
                                                   const unsigned short* __restrict__ XT,
                                                   const float* __restrict__ bias,
                                                   float* __restrict__ out) {
    __shared__ __align__(16) unsigned short As[BM * BK];  // [m][k], k contiguous
    __shared__ __align__(16) unsigned short Bs[BN * BK];  // [n][k], k contiguous

    int t = threadIdx.x;
    int w = t >> 6;            // wave 0..3
    int l = t & 63;
    int wm = (w >> 1) * 64;    // wave m-offset in tile
    int wn = (w & 1) * 64;     // wave n-offset in tile
    int lane16 = l & 15;
    int quad = l >> 4;
    int m0 = blockIdx.y * BM;
    int n0 = blockIdx.x * BN;

    f32x4 acc[4][4] = {};

    // Staging: each wave stages 32 rows of A and 32 rows of B per K-step.
    // global_load_lds: lane i lands at lds_base + i*16B, so lane i must read
    // global row (i>>2), k-quad (i&3): LDS stays exactly [row][k] linear.
    int srow = l >> 2;         // 0..15
    int scol = (l & 3) * 8;    // element offset within row
    int rb = w * 32;
    const unsigned short* gA0 = Wb + (long long)(m0 + rb + srow) * K_DIM + scol;
    const unsigned short* gA1 = gA0 + 16LL * K_DIM;
    const unsigned short* gB0 = XT + (long long)(n0 + rb + srow) * K_DIM + scol;
    const unsigned short* gB1 = gB0 + 16LL * K_DIM;
    unsigned short* lA0 = &As[rb * BK];         // wave-uniform LDS bases
    unsigned short* lA1 = &As[(rb + 16) * BK];
    unsigned short* lB0 = &Bs[rb * BK];
    unsigned short* lB1 = &Bs[(rb + 16) * BK];

    for (int kt = 0; kt < K_DIM / BK; ++kt) {
        async16(gA0, lA0);
        async16(gA1, lA1);
        async16(gB0, lB0);
        async16(gB1, lB1);
        gA0 += BK; gA1 += BK; gB0 += BK; gB1 += BK;
        __builtin_amdgcn_s_waitcnt(0);  // drain vmcnt before LDS reads
        __syncthreads();

        bf16x8 a[4], b[4];
#pragma unroll
        for (int i = 0; i < 4; ++i)
            a[i] = *(const bf16x8*)&As[(wm + i * 16 + lane16) * BK + quad * 8];
#pragma unroll
        for (int j = 0; j < 4; ++j)
            b[j] = *(const bf16x8*)&Bs[(wn + j * 16 + lane16) * BK + quad * 8];

#pragma unroll
        for (int i = 0; i < 4; ++i)
#pragma unroll
            for (int j = 0; j < 4; ++j)
                acc[i][j] = __builtin_amdgcn_mfma_f32_16x16x32_bf16(a[i], b[j], acc[i][j], 0, 0, 0);

        __syncthreads();  // protect LDS before next stage overwrites
    }

    // Epilogue: C/D layout col = lane&15, row = quad*4 + reg  [m89-verified]
#pragma unroll
    for (int j = 0; j < 4; ++j) {
        int n = n0 + wn + j * 16 + lane16;
        if (n >= N_REAL) continue;
        float bv = bias[n];
#pragma unroll
        for (int i = 0; i < 4; ++i) {
            int mbase = m0 + wm + i * 16 + quad * 4;
#pragma unroll
            for (int r = 0; r < 4; ++r) {
                int m = mbase + r;
                if (m < M_REAL)
                    out[(long long)m * N_REAL + n] = acc[i][j][r] + bv;
            }
        }
    }
}

// ---------------------------------------------------------------------------
extern "C" void kernel_launch(void* const* d_in, const int* in_sizes, int n_in,
                              void* d_out, int out_size, void* d_ws, size_t ws_size,
                              hipStream_t stream) {
    const float* W    = (const float*)d_in[0];  // [2000][8192]
    const float* bias = (const float*)d_in[1];  // [2000]
    const float* X    = (const float*)d_in[2];  // [8192][2000]
    float* out = (float*)d_out;

    unsigned short* Wb = (unsigned short*)d_ws;                    // [2048][8192] bf16
    unsigned short* XT = Wb + (long long)M_PAD * K_DIM;            // [2048][8192] bf16

    conv_w_kernel<<<(M_PAD * K_DIM) / (8 * 256), 256, 0, stream>>>(W, Wb);

    dim3 tgrid(K_DIM / 64, N_PAD / 64);
    conv_xt_kernel<<<tgrid, 256, 0, stream>>>(X, XT);

    dim3 ggrid(N_PAD / BN, M_PAD / BM);
    gemm_kernel<<<ggrid, 256, 0, stream>>>(Wb, XT, bias, out);
}

// Round 2
// 288.777 us; speedup vs baseline: 1.0595x; 1.0595x over previous
//
#include <hip/hip_runtime.h>

#define K_DIM 8192
#define M_REAL 2000
#define N_REAL 2000
#define M_PAD 2048
#define N_PAD 2048

#define BM 128
#define BN 128
#define BK 32
#define SPLITK 4
#define KSLAB (K_DIM / SPLITK)   // 2048

// prep kernel block ranges
#define NB_CONVW 8192            // 2048*8192/(8*256)
#define NB_CONVX 4096            // (8192/64) * (2048/64)
#define NB_INIT  3907            // ceil(2000*500/256)

typedef __bf16 bf16x8 __attribute__((ext_vector_type(8)));
typedef float f32x4 __attribute__((ext_vector_type(4)));

__device__ __forceinline__ unsigned short f2bf(float f) {
    union { float f; unsigned u; } v; v.f = f;
    unsigned r = v.u + 0x7FFFu + ((v.u >> 16) & 1u);  // RNE; inputs are finite normals
    return (unsigned short)(r >> 16);
}

__device__ __forceinline__ void async16(const void* g, void* l) {
    __builtin_amdgcn_global_load_lds((__attribute__((address_space(1))) void*)(g),
                                     (__attribute__((address_space(3))) void*)(l),
                                     16, 0, 0);
}

// ---------------------------------------------------------------------------
// Fused prep: [0,NB_CONVW)            W f32 -> Wb bf16 [2048][8192], pad rows 0
//             [NB_CONVW,+NB_CONVX)    X [8192][2000] f32 -> XT bf16 [2048][8192]
//             [then, +NB_INIT)        out[m][n] = bias[n]  (bias pre-fill)
__global__ __launch_bounds__(256) void prep_kernel(const float* __restrict__ W,
                                                   const float* __restrict__ X,
                                                   const float* __restrict__ bias,
                                                   unsigned short* __restrict__ Wb,
                                                   unsigned short* __restrict__ XT,
                                                   float* __restrict__ out) {
    __shared__ unsigned short tile[64][65];
    int bid = blockIdx.x;
    if (bid < NB_CONVW) {
        long long t = (long long)bid * 256 + threadIdx.x;
        long long e = t * 8;
        int m = (int)(e >> 13);
        ushort4 o0 = make_ushort4(0, 0, 0, 0), o1 = o0;
        if (m < M_REAL) {
            const float4* src = (const float4*)(W + e);
            float4 f0 = src[0], f1 = src[1];
            o0.x = f2bf(f0.x); o0.y = f2bf(f0.y); o0.z = f2bf(f0.z); o0.w = f2bf(f0.w);
            o1.x = f2bf(f1.x); o1.y = f2bf(f1.y); o1.z = f2bf(f1.z); o1.w = f2bf(f1.w);
        }
        *(ushort4*)(Wb + e) = o0;
        *(ushort4*)(Wb + e + 4) = o1;
    } else if (bid < NB_CONVW + NB_CONVX) {
        int b2 = bid - NB_CONVW;
        int k0 = (b2 & 127) * 64;
        int n0 = (b2 >> 7) * 64;
        int tx = threadIdx.x & 63;
        int ty = threadIdx.x >> 6;
        int n = n0 + tx;
#pragma unroll
        for (int it = 0; it < 16; ++it) {
            int k = k0 + ty + it * 4;
            float v = (n < N_REAL) ? X[(long long)k * N_REAL + n] : 0.0f;
            tile[ty + it * 4][tx] = f2bf(v);
        }
        __syncthreads();
        int kx = (threadIdx.x & 31) * 2;
        int ny = threadIdx.x >> 5;
#pragma unroll
        for (int it = 0; it < 8; ++it) {
            int nn = ny + it * 8;
            unsigned a = tile[kx][nn];
            unsigned b = tile[kx + 1][nn];
            *(unsigned*)(&XT[(long long)(n0 + nn) * K_DIM + k0 + kx]) = a | (b << 16);
        }
    } else {
        int t = (bid - NB_CONVW - NB_CONVX) * 256 + threadIdx.x;
        if (t < M_REAL * (N_REAL / 4)) {
            int m = t / (N_REAL / 4);
            int n4 = t - m * (N_REAL / 4);
            float4 bv = *(const float4*)(bias + n4 * 4);
            *(float4*)(out + (long long)m * N_REAL + n4 * 4) = bv;
        }
    }
}

// ---------------------------------------------------------------------------
// Split-K GEMM: out[m][n] += sum_{k in slab z} Wb[m][k] * XT[n][k]  (atomic)
// 128x128 tile, BK=32, 4 waves x (4x4 of 16x16x32 bf16 MFMA).
__global__ __launch_bounds__(256) void gemm_kernel(const unsigned short* __restrict__ Wb,
                                                   const unsigned short* __restrict__ XT,
                                                   float* __restrict__ out) {
    __shared__ __align__(16) unsigned short As[BM * BK];  // [m][k], k contiguous
    __shared__ __align__(16) unsigned short Bs[BN * BK];  // [n][k], k contiguous

    int t = threadIdx.x;
    int w = t >> 6;
    int l = t & 63;
    int wm = (w >> 1) * 64;
    int wn = (w & 1) * 64;
    int lane16 = l & 15;
    int quad = l >> 4;
    int m0 = blockIdx.y * BM;
    int n0 = blockIdx.x * BN;
    int ks = blockIdx.z * KSLAB;

    f32x4 acc[4][4] = {};

    // global_load_lds: lane i -> lds_base + i*16B; lane i reads row (i>>2), k-quad (i&3)
    int srow = l >> 2;
    int scol = (l & 3) * 8;
    int rb = w * 32;
    const unsigned short* gA0 = Wb + (long long)(m0 + rb + srow) * K_DIM + ks + scol;
    const unsigned short* gA1 = gA0 + 16LL * K_DIM;
    const unsigned short* gB0 = XT + (long long)(n0 + rb + srow) * K_DIM + ks + scol;
    const unsigned short* gB1 = gB0 + 16LL * K_DIM;
    unsigned short* lA0 = &As[rb * BK];
    unsigned short* lA1 = &As[(rb + 16) * BK];
    unsigned short* lB0 = &Bs[rb * BK];
    unsigned short* lB1 = &Bs[(rb + 16) * BK];

    for (int kt = 0; kt < KSLAB / BK; ++kt) {
        async16(gA0, lA0);
        async16(gA1, lA1);
        async16(gB0, lB0);
        async16(gB1, lB1);
        gA0 += BK; gA1 += BK; gB0 += BK; gB1 += BK;
        __builtin_amdgcn_s_waitcnt(0);
        __syncthreads();

        bf16x8 a[4], b[4];
#pragma unroll
        for (int i = 0; i < 4; ++i)
            a[i] = *(const bf16x8*)&As[(wm + i * 16 + lane16) * BK + quad * 8];
#pragma unroll
        for (int j = 0; j < 4; ++j)
            b[j] = *(const bf16x8*)&Bs[(wn + j * 16 + lane16) * BK + quad * 8];

#pragma unroll
        for (int i = 0; i < 4; ++i)
#pragma unroll
            for (int j = 0; j < 4; ++j)
                acc[i][j] = __builtin_amdgcn_mfma_f32_16x16x32_bf16(a[i], b[j], acc[i][j], 0, 0, 0);

        __syncthreads();
    }

    // Epilogue: C/D layout col = lane&15, row = quad*4 + reg  [m89-verified]
#pragma unroll
    for (int j = 0; j < 4; ++j) {
        int n = n0 + wn + j * 16 + lane16;
        if (n >= N_REAL) continue;
#pragma unroll
        for (int i = 0; i < 4; ++i) {
            int mbase = m0 + wm + i * 16 + quad * 4;
#pragma unroll
            for (int r = 0; r < 4; ++r) {
                int m = mbase + r;
                if (m < M_REAL)
                    atomicAdd(&out[(long long)m * N_REAL + n], acc[i][j][r]);
            }
        }
    }
}

// ---------------------------------------------------------------------------
extern "C" void kernel_launch(void* const* d_in, const int* in_sizes, int n_in,
                              void* d_out, int out_size, void* d_ws, size_t ws_size,
                              hipStream_t stream) {
    const float* W    = (const float*)d_in[0];  // [2000][8192]
    const float* bias = (const float*)d_in[1];  // [2000]
    const float* X    = (const float*)d_in[2];  // [8192][2000]
    float* out = (float*)d_out;

    unsigned short* Wb = (unsigned short*)d_ws;                 // [2048][8192] bf16
    unsigned short* XT = Wb + (long long)M_PAD * K_DIM;         // [2048][8192] bf16

    prep_kernel<<<NB_CONVW + NB_CONVX + NB_INIT, 256, 0, stream>>>(W, X, bias, Wb, XT, out);

    dim3 ggrid(N_PAD / BN, M_PAD / BM, SPLITK);
    gemm_kernel<<<ggrid, 256, 0, stream>>>(Wb, XT, out);
}

// Round 3
// 283.763 us; speedup vs baseline: 1.0782x; 1.0177x over previous
//
#include <hip/hip_runtime.h>

#define K_DIM 8192
#define M_REAL 2000
#define N_REAL 2000
#define M_PAD 2048
#define N_PAD 2048

#define BM 128
#define BN 128
#define BK 32
#define SPLITK 4
#define KSLAB (K_DIM / SPLITK)   // 2048

// prep kernel block ranges
#define NB_CONVW 8192            // 2048*8192/(8*256)
#define NB_CONVX 4096            // (8192/64) * (2048/64)
#define NB_INIT  3907            // ceil(2000*500/256)

typedef __bf16 bf16x8 __attribute__((ext_vector_type(8)));
typedef float f32x4 __attribute__((ext_vector_type(4)));

__device__ __forceinline__ unsigned short f2bf(float f) {
    union { float f; unsigned u; } v; v.f = f;
    unsigned r = v.u + 0x7FFFu + ((v.u >> 16) & 1u);  // RNE; inputs are finite normals
    return (unsigned short)(r >> 16);
}

__device__ __forceinline__ void async16(const void* g, void* l) {
    __builtin_amdgcn_global_load_lds((__attribute__((address_space(1))) void*)(g),
                                     (__attribute__((address_space(3))) void*)(l),
                                     16, 0, 0);
}

// ---------------------------------------------------------------------------
// Fused prep: [0,NB_CONVW)            W f32 -> Wb bf16 [2048][8192], pad rows 0
//             [NB_CONVW,+NB_CONVX)    X [8192][2000] f32 -> XT bf16 [2048][8192]
//             [then, +NB_INIT)        out[m][n] = bias[n]  (bias pre-fill)
__global__ __launch_bounds__(256) void prep_kernel(const float* __restrict__ W,
                                                   const float* __restrict__ X,
                                                   const float* __restrict__ bias,
                                                   unsigned short* __restrict__ Wb,
                                                   unsigned short* __restrict__ XT,
                                                   float* __restrict__ out) {
    __shared__ unsigned short tile[64][65];
    int bid = blockIdx.x;
    if (bid < NB_CONVW) {
        long long t = (long long)bid * 256 + threadIdx.x;
        long long e = t * 8;
        int m = (int)(e >> 13);
        ushort4 o0 = make_ushort4(0, 0, 0, 0), o1 = o0;
        if (m < M_REAL) {
            const float4* src = (const float4*)(W + e);
            float4 f0 = src[0], f1 = src[1];
            o0.x = f2bf(f0.x); o0.y = f2bf(f0.y); o0.z = f2bf(f0.z); o0.w = f2bf(f0.w);
            o1.x = f2bf(f1.x); o1.y = f2bf(f1.y); o1.z = f2bf(f1.z); o1.w = f2bf(f1.w);
        }
        *(ushort4*)(Wb + e) = o0;
        *(ushort4*)(Wb + e + 4) = o1;
    } else if (bid < NB_CONVW + NB_CONVX) {
        int b2 = bid - NB_CONVW;
        int k0 = (b2 & 127) * 64;
        int n0 = (b2 >> 7) * 64;
        int tx = threadIdx.x & 63;
        int ty = threadIdx.x >> 6;
        int n = n0 + tx;
#pragma unroll
        for (int it = 0; it < 16; ++it) {
            int k = k0 + ty + it * 4;
            float v = (n < N_REAL) ? X[(long long)k * N_REAL + n] : 0.0f;
            tile[ty + it * 4][tx] = f2bf(v);
        }
        __syncthreads();
        int kx = (threadIdx.x & 31) * 2;
        int ny = threadIdx.x >> 5;
#pragma unroll
        for (int it = 0; it < 8; ++it) {
            int nn = ny + it * 8;
            unsigned a = tile[kx][nn];
            unsigned b = tile[kx + 1][nn];
            *(unsigned*)(&XT[(long long)(n0 + nn) * K_DIM + k0 + kx]) = a | (b << 16);
        }
    } else {
        int t = (bid - NB_CONVW - NB_CONVX) * 256 + threadIdx.x;
        if (t < M_REAL * (N_REAL / 4)) {
            int m = t / (N_REAL / 4);
            int n4 = t - m * (N_REAL / 4);
            float4 bv = *(const float4*)(bias + n4 * 4);
            *(float4*)(out + (long long)m * N_REAL + n4 * 4) = bv;
        }
    }
}

// ---------------------------------------------------------------------------
// Split-K GEMM with XCD-aware swizzle.
// 1-D grid of 1024; dispatcher assigns xcd = flat % 8 (round-robin), so
// decode flat -> (xcd, local) and give each XCD a compact 4(x) x 8(y) x 4(z)
// region = 128 blocks = exactly its residency (32 CU x 4 blocks). Staging
// then hits the XCD-local 4 MB L2 instead of bouncing through L3.
__global__ __launch_bounds__(256) void gemm_kernel(const unsigned short* __restrict__ Wb,
                                                   const unsigned short* __restrict__ XT,
                                                   float* __restrict__ out) {
    __shared__ __align__(16) unsigned short As[BM * BK];  // [m][k], k contiguous
    __shared__ __align__(16) unsigned short Bs[BN * BK];  // [n][k], k contiguous

    int f = blockIdx.x;
    int xcd = f & 7;
    int local = f >> 3;            // 0..127 within XCD
    int lz = local & 3;
    int lx = (local >> 2) & 3;
    int ly = local >> 4;           // 0..7
    int bx = (xcd & 3) * 4 + lx;   // 0..15
    int by = (xcd >> 2) * 8 + ly;  // 0..15
    int bz = lz;

    int t = threadIdx.x;
    int w = t >> 6;
    int l = t & 63;
    int wm = (w >> 1) * 64;
    int wn = (w & 1) * 64;
    int lane16 = l & 15;
    int quad = l >> 4;
    int m0 = by * BM;
    int n0 = bx * BN;
    int ks = bz * KSLAB;

    f32x4 acc[4][4] = {};

    // global_load_lds: lane i -> lds_base + i*16B; lane i reads row (i>>2), k-quad (i&3)
    int srow = l >> 2;
    int scol = (l & 3) * 8;
    int rb = w * 32;
    const unsigned short* gA0 = Wb + (long long)(m0 + rb + srow) * K_DIM + ks + scol;
    const unsigned short* gA1 = gA0 + 16LL * K_DIM;
    const unsigned short* gB0 = XT + (long long)(n0 + rb + srow) * K_DIM + ks + scol;
    const unsigned short* gB1 = gB0 + 16LL * K_DIM;
    unsigned short* lA0 = &As[rb * BK];
    unsigned short* lA1 = &As[(rb + 16) * BK];
    unsigned short* lB0 = &Bs[rb * BK];
    unsigned short* lB1 = &Bs[(rb + 16) * BK];

    for (int kt = 0; kt < KSLAB / BK; ++kt) {
        async16(gA0, lA0);
        async16(gA1, lA1);
        async16(gB0, lB0);
        async16(gB1, lB1);
        gA0 += BK; gA1 += BK; gB0 += BK; gB1 += BK;
        __builtin_amdgcn_s_waitcnt(0);
        __syncthreads();

        bf16x8 a[4], b[4];
#pragma unroll
        for (int i = 0; i < 4; ++i)
            a[i] = *(const bf16x8*)&As[(wm + i * 16 + lane16) * BK + quad * 8];
#pragma unroll
        for (int j = 0; j < 4; ++j)
            b[j] = *(const bf16x8*)&Bs[(wn + j * 16 + lane16) * BK + quad * 8];

#pragma unroll
        for (int i = 0; i < 4; ++i)
#pragma unroll
            for (int j = 0; j < 4; ++j)
                acc[i][j] = __builtin_amdgcn_mfma_f32_16x16x32_bf16(a[i], b[j], acc[i][j], 0, 0, 0);

        __syncthreads();
    }

    // Epilogue: C/D layout col = lane&15, row = quad*4 + reg  [m89-verified]
#pragma unroll
    for (int j = 0; j < 4; ++j) {
        int n = n0 + wn + j * 16 + lane16;
        if (n >= N_REAL) continue;
#pragma unroll
        for (int i = 0; i < 4; ++i) {
            int mbase = m0 + wm + i * 16 + quad * 4;
#pragma unroll
            for (int r = 0; r < 4; ++r) {
                int m = mbase + r;
                if (m < M_REAL)
                    atomicAdd(&out[(long long)m * N_REAL + n], acc[i][j][r]);
            }
        }
    }
}

// ---------------------------------------------------------------------------
extern "C" void kernel_launch(void* const* d_in, const int* in_sizes, int n_in,
                              void* d_out, int out_size, void* d_ws, size_t ws_size,
                              hipStream_t stream) {
    const float* W    = (const float*)d_in[0];  // [2000][8192]
    const float* bias = (const float*)d_in[1];  // [2000]
    const float* X    = (const float*)d_in[2];  // [8192][2000]
    float* out = (float*)d_out;

    unsigned short* Wb = (unsigned short*)d_ws;                 // [2048][8192] bf16
    unsigned short* XT = Wb + (long long)M_PAD * K_DIM;         // [2048][8192] bf16

    prep_kernel<<<NB_CONVW + NB_CONVX + NB_INIT, 256, 0, stream>>>(W, X, bias, Wb, XT, out);

    gemm_kernel<<<(N_PAD / BN) * (M_PAD / BM) * SPLITK, 256, 0, stream>>>(Wb, XT, out);
}

// Round 4
// 275.881 us; speedup vs baseline: 1.1090x; 1.0286x over previous
//
#include <hip/hip_runtime.h>

#define K_DIM 8192
#define M_REAL 2000
#define N_REAL 2000
#define M_PAD 2048
#define N_PAD 2048

#define BM 256
#define BN 256
#define BK 32
#define SPLITK 4
#define KSLAB (K_DIM / SPLITK)   // 2048
#define NIT (KSLAB / BK)         // 64

#define NB_CONVW 8192            // 2048*8192/(8*256)
#define NB_INIT  3907            // ceil(2000*500/256)

typedef __bf16 bf16x8 __attribute__((ext_vector_type(8)));
typedef float f32x4 __attribute__((ext_vector_type(4)));

#define RAW_BARRIER()  asm volatile("s_barrier" ::: "memory")
#define WAIT_VM4()     asm volatile("s_waitcnt vmcnt(4)" ::: "memory")
#define WAIT_VM0()     asm volatile("s_waitcnt vmcnt(0)" ::: "memory")

__device__ __forceinline__ unsigned short f2bf(float f) {
    union { float f; unsigned u; } v; v.f = f;
    unsigned r = v.u + 0x7FFFu + ((v.u >> 16) & 1u);  // RNE; inputs are finite normals
    return (unsigned short)(r >> 16);
}

__device__ __forceinline__ void async16(const void* g, void* l) {
    __builtin_amdgcn_global_load_lds((__attribute__((address_space(1))) void*)(g),
                                     (__attribute__((address_space(3))) void*)(l),
                                     16, 0, 0);
}

// ---------------------------------------------------------------------------
// W [2000][8192] f32 -> Wb [2048][8192] bf16, pad rows zeroed.
__global__ __launch_bounds__(256) void conv_w_kernel(const float* __restrict__ W,
                                                     unsigned short* __restrict__ Wb) {
    long long t = (long long)blockIdx.x * 256 + threadIdx.x;
    long long e = t * 8;
    int m = (int)(e >> 13);
    ushort4 o0 = make_ushort4(0, 0, 0, 0), o1 = o0;
    if (m < M_REAL) {
        const float4* src = (const float4*)(W + e);
        float4 f0 = src[0], f1 = src[1];
        o0.x = f2bf(f0.x); o0.y = f2bf(f0.y); o0.z = f2bf(f0.z); o0.w = f2bf(f0.w);
        o1.x = f2bf(f1.x); o1.y = f2bf(f1.y); o1.z = f2bf(f1.z); o1.w = f2bf(f1.w);
    }
    *(ushort4*)(Wb + e) = o0;
    *(ushort4*)(Wb + e + 4) = o1;
}

// ---------------------------------------------------------------------------
// X [8192][2000] f32 -> XT [2048][8192] bf16 (XT[n][k] = X[k][n]), pad rows 0.
// 64x64 tile; float4 coalesced reads, ushort4 LDS + global writes.
__global__ __launch_bounds__(256) void conv_xt_kernel(const float* __restrict__ X,
                                                      unsigned short* __restrict__ XT) {
    __shared__ unsigned short tile[64][68];   // [k-k0][n-n0], +4 pad
    int k0 = blockIdx.x * 64;
    int n0 = blockIdx.y * 64;
    int t = threadIdx.x;
    int c16 = t & 15, r16 = t >> 4;
#pragma unroll
    for (int it = 0; it < 4; ++it) {
        int k = k0 + r16 + it * 16;
        int n = n0 + c16 * 4;
        float4 v = make_float4(0.f, 0.f, 0.f, 0.f);
        if (n < N_REAL) v = *(const float4*)(X + (long long)k * N_REAL + n);
        ushort4 o;
        o.x = f2bf(v.x); o.y = f2bf(v.y); o.z = f2bf(v.z); o.w = f2bf(v.w);
        *(ushort4*)&tile[r16 + it * 16][c16 * 4] = o;
    }
    __syncthreads();
#pragma unroll
    for (int it = 0; it < 4; ++it) {
        int nn = r16 + it * 16;           // n - n0
        int k4 = c16 * 4;
        ushort4 o;
        o.x = tile[k4 + 0][nn];
        o.y = tile[k4 + 1][nn];
        o.z = tile[k4 + 2][nn];
        o.w = tile[k4 + 3][nn];
        *(ushort4*)(XT + (long long)(n0 + nn) * K_DIM + k0 + k4) = o;
    }
}

// ---------------------------------------------------------------------------
// out[m][n] = bias[n]
__global__ __launch_bounds__(256) void bias_kernel(const float* __restrict__ bias,
                                                   float* __restrict__ out) {
    int t = blockIdx.x * 256 + threadIdx.x;
    if (t < M_REAL * (N_REAL / 4)) {
        int m = t / (N_REAL / 4);
        int n4 = t - m * (N_REAL / 4);
        float4 bv = *(const float4*)(bias + n4 * 4);
        *(float4*)(out + (long long)m * N_REAL + n4 * 4) = bv;
    }
}

// ---------------------------------------------------------------------------
// Split-K GEMM, 256x256 tile (halves LDS-staging bytes vs 128x128), BK=32,
// double-buffered LDS with raw s_barrier + vmcnt(4) so next-tile DMA overlaps
// MFMA. 8 waves x (8x4 MFMA 16x16x32). XCD swizzle: f&7 round-robin.
__global__ __launch_bounds__(512, 2) void gemm_kernel(const unsigned short* __restrict__ Wb,
                                                      const unsigned short* __restrict__ XT,
                                                      float* __restrict__ out) {
    __shared__ __align__(16) unsigned short As[2][BM * BK];  // 2 x 16 KB
    __shared__ __align__(16) unsigned short Bs[2][BN * BK];  // 2 x 16 KB

    int f = blockIdx.x;
    int xcd = f & 7;
    int local = f >> 3;                    // 0..31
    int bz = local & 3;
    int bx = (xcd & 3) * 2 + ((local >> 2) & 1);   // 0..7
    int by = (xcd >> 2) * 4 + (local >> 3);        // 0..7

    int t = threadIdx.x;
    int w = t >> 6;              // 0..7
    int l = t & 63;
    int wm = (w >> 2) * 128;     // 0 or 128
    int wn = (w & 3) * 64;       // 0,64,128,192
    int lane16 = l & 15;
    int quad = l >> 4;
    int m0 = by * BM;
    int n0 = bx * BN;
    int ks = bz * KSLAB;

    f32x4 acc[8][4] = {};

    // Staging: each wave stages 32 rows of A and 32 rows of B per K-step.
    // global_load_lds: lane i -> lds_base + i*16B; lane i reads row (i>>2), k-quad (i&3)
    int srow = l >> 2;
    int scol = (l & 3) * 8;
    int rb = w * 32;
    const unsigned short* gA0 = Wb + (long long)(m0 + rb + srow) * K_DIM + ks + scol;
    const unsigned short* gA1 = gA0 + 16LL * K_DIM;
    const unsigned short* gB0 = XT + (long long)(n0 + rb + srow) * K_DIM + ks + scol;
    const unsigned short* gB1 = gB0 + 16LL * K_DIM;

    // Prologue: stage tile 0 into buf 0
    async16(gA0, &As[0][rb * BK]);
    async16(gA1, &As[0][(rb + 16) * BK]);
    async16(gB0, &Bs[0][rb * BK]);
    async16(gB1, &Bs[0][(rb + 16) * BK]);
    gA0 += BK; gA1 += BK; gB0 += BK; gB1 += BK;

    for (int kt = 0; kt < NIT; ++kt) {
        int cur = kt & 1;
        if (kt + 1 < NIT) {
            int nxt = cur ^ 1;
            async16(gA0, &As[nxt][rb * BK]);
            async16(gA1, &As[nxt][(rb + 16) * BK]);
            async16(gB0, &Bs[nxt][rb * BK]);
            async16(gB1, &Bs[nxt][(rb + 16) * BK]);
            gA0 += BK; gA1 += BK; gB0 += BK; gB1 += BK;
            WAIT_VM4();   // own buf[cur] loads complete; next 4 stay in flight
        } else {
            WAIT_VM0();
        }
        RAW_BARRIER();    // all waves' buf[cur] loads complete

        bf16x8 a[8], b[4];
#pragma unroll
        for (int i = 0; i < 8; ++i)
            a[i] = *(const bf16x8*)&As[cur][(wm + i * 16 + lane16) * BK + quad * 8];
#pragma unroll
        for (int j = 0; j < 4; ++j)
            b[j] = *(const bf16x8*)&Bs[cur][(wn + j * 16 + lane16) * BK + quad * 8];

#pragma unroll
        for (int i = 0; i < 8; ++i)
#pragma unroll
            for (int j = 0; j < 4; ++j)
                acc[i][j] = __builtin_amdgcn_mfma_f32_16x16x32_bf16(a[i], b[j], acc[i][j], 0, 0, 0);

        if (kt + 1 < NIT)
            RAW_BARRIER();  // all waves done reading buf[cur] before it's re-staged
    }

    // Epilogue: C/D layout col = lane&15, row = quad*4 + reg  [m89-verified]
#pragma unroll
    for (int j = 0; j < 4; ++j) {
        int n = n0 + wn + j * 16 + lane16;
        if (n >= N_REAL) continue;
#pragma unroll
        for (int i = 0; i < 8; ++i) {
            int mbase = m0 + wm + i * 16 + quad * 4;
#pragma unroll
            for (int r = 0; r < 4; ++r) {
                int m = mbase + r;
                if (m < M_REAL)
                    atomicAdd(&out[(long long)m * N_REAL + n], acc[i][j][r]);
            }
        }
    }
}

// ---------------------------------------------------------------------------
extern "C" void kernel_launch(void* const* d_in, const int* in_sizes, int n_in,
                              void* d_out, int out_size, void* d_ws, size_t ws_size,
                              hipStream_t stream) {
    const float* W    = (const float*)d_in[0];  // [2000][8192]
    const float* bias = (const float*)d_in[1];  // [2000]
    const float* X    = (const float*)d_in[2];  // [8192][2000]
    float* out = (float*)d_out;

    unsigned short* Wb = (unsigned short*)d_ws;                 // [2048][8192] bf16
    unsigned short* XT = Wb + (long long)M_PAD * K_DIM;         // [2048][8192] bf16

    conv_w_kernel<<<NB_CONVW, 256, 0, stream>>>(W, Wb);
    dim3 tgrid(K_DIM / 64, N_PAD / 64);
    conv_xt_kernel<<<tgrid, 256, 0, stream>>>(X, XT);
    bias_kernel<<<NB_INIT, 256, 0, stream>>>(bias, out);

    gemm_kernel<<<(N_PAD / BN) * (M_PAD / BM) * SPLITK, 512, 0, stream>>>(Wb, XT, out);
}

// Round 6
// 266.924 us; speedup vs baseline: 1.1463x; 1.0336x over previous
//
#include <hip/hip_runtime.h>

#define K_DIM 8192
#define M_REAL 2000
#define N_REAL 2000
#define M_PAD 2048
#define N_PAD 2048

#define BM 256
#define BN 256
#define BK 32
#define SPLITK 4
#define KSLAB (K_DIM / SPLITK)   // 2048
#define NIT (KSLAB / BK)         // 64

// fused prep block ranges
#define NB_CONVW 16384           // 2048*8192/(4*256)
#define NB_CONVX 4096            // (8192/64) * (2048/64)
#define NB_INIT  3907            // ceil(2000*500/256)

typedef __bf16 bf16x8 __attribute__((ext_vector_type(8)));
typedef float f32x4 __attribute__((ext_vector_type(4)));
typedef float fvec4 __attribute__((ext_vector_type(4)));   // for nontemporal builtins

#define RAW_BARRIER()  asm volatile("s_barrier" ::: "memory")
#define WAIT_VM4()     asm volatile("s_waitcnt vmcnt(4)" ::: "memory")
#define WAIT_VM0()     asm volatile("s_waitcnt vmcnt(0)" ::: "memory")

__device__ __forceinline__ unsigned short f2bf(float f) {
    union { float f; unsigned u; } v; v.f = f;
    unsigned r = v.u + 0x7FFFu + ((v.u >> 16) & 1u);  // RNE; inputs are finite normals
    return (unsigned short)(r >> 16);
}

__device__ __forceinline__ void async16(const void* g, void* l) {
    __builtin_amdgcn_global_load_lds((__attribute__((address_space(1))) void*)(g),
                                     (__attribute__((address_space(3))) void*)(l),
                                     16, 0, 0);
}

// ---------------------------------------------------------------------------
// Fused prep (single dispatch so its counters are visible in top-5):
//   [0, NB_CONVW)       W f32 -> Wb bf16 [2048][8192]; lane reads contiguous
//                       fvec4 (16B), writes contiguous ushort4 (8B)
//   [+NB_CONVX)         X [8192][2000] f32 -> XT bf16 [2048][8192] (transpose)
//   [+NB_INIT)          out[m][n] = bias[n]
__global__ __launch_bounds__(256) void prep_kernel(const float* __restrict__ W,
                                                   const float* __restrict__ X,
                                                   const float* __restrict__ bias,
                                                   unsigned short* __restrict__ Wb,
                                                   unsigned short* __restrict__ XT,
                                                   float* __restrict__ out) {
    __shared__ unsigned short tile[64][68];
    int bid = blockIdx.x;
    if (bid < NB_CONVW) {
        long long t = (long long)bid * 256 + threadIdx.x;
        long long e = t * 4;                  // 4 elements per thread
        int m = (int)(e >> 13);
        ushort4 o = make_ushort4(0, 0, 0, 0);
        if (m < M_REAL) {
            fvec4 f = __builtin_nontemporal_load((const fvec4*)(W + e));
            o.x = f2bf(f.x); o.y = f2bf(f.y); o.z = f2bf(f.z); o.w = f2bf(f.w);
        }
        *(ushort4*)(Wb + e) = o;
    } else if (bid < NB_CONVW + NB_CONVX) {
        int b2 = bid - NB_CONVW;
        int k0 = (b2 & 127) * 64;
        int n0 = (b2 >> 7) * 64;
        int t = threadIdx.x;
        int c16 = t & 15, r16 = t >> 4;
#pragma unroll
        for (int it = 0; it < 4; ++it) {
            int k = k0 + r16 + it * 16;
            int n = n0 + c16 * 4;
            fvec4 v = {0.f, 0.f, 0.f, 0.f};
            if (n < N_REAL)
                v = __builtin_nontemporal_load((const fvec4*)(X + (long long)k * N_REAL + n));
            ushort4 o;
            o.x = f2bf(v.x); o.y = f2bf(v.y); o.z = f2bf(v.z); o.w = f2bf(v.w);
            *(ushort4*)&tile[r16 + it * 16][c16 * 4] = o;
        }
        __syncthreads();
#pragma unroll
        for (int it = 0; it < 4; ++it) {
            int nn = r16 + it * 16;           // n - n0
            int k4 = c16 * 4;
            ushort4 o;
            o.x = tile[k4 + 0][nn];
            o.y = tile[k4 + 1][nn];
            o.z = tile[k4 + 2][nn];
            o.w = tile[k4 + 3][nn];
            *(ushort4*)(XT + (long long)(n0 + nn) * K_DIM + k0 + k4) = o;
        }
    } else {
        int t = (bid - NB_CONVW - NB_CONVX) * 256 + threadIdx.x;
        if (t < M_REAL * (N_REAL / 4)) {
            int m = t / (N_REAL / 4);
            int n4 = t - m * (N_REAL / 4);
            float4 bv = *(const float4*)(bias + n4 * 4);
            *(float4*)(out + (long long)m * N_REAL + n4 * 4) = bv;
        }
    }
}

// ---------------------------------------------------------------------------
// Split-K GEMM, 256x256 tile, BK=32, double-buffered LDS with raw s_barrier +
// vmcnt(4). 8 waves x (8x4 MFMA 16x16x32). XCD swizzle: f&7 round-robin.
// UNCHANGED from round 4 (control).
__global__ __launch_bounds__(512, 2) void gemm_kernel(const unsigned short* __restrict__ Wb,
                                                      const unsigned short* __restrict__ XT,
                                                      float* __restrict__ out) {
    __shared__ __align__(16) unsigned short As[2][BM * BK];  // 2 x 16 KB
    __shared__ __align__(16) unsigned short Bs[2][BN * BK];  // 2 x 16 KB

    int f = blockIdx.x;
    int xcd = f & 7;
    int local = f >> 3;                    // 0..31
    int bz = local & 3;
    int bx = (xcd & 3) * 2 + ((local >> 2) & 1);   // 0..7
    int by = (xcd >> 2) * 4 + (local >> 3);        // 0..7

    int t = threadIdx.x;
    int w = t >> 6;              // 0..7
    int l = t & 63;
    int wm = (w >> 2) * 128;     // 0 or 128
    int wn = (w & 3) * 64;       // 0,64,128,192
    int lane16 = l & 15;
    int quad = l >> 4;
    int m0 = by * BM;
    int n0 = bx * BN;
    int ks = bz * KSLAB;

    f32x4 acc[8][4] = {};

    int srow = l >> 2;
    int scol = (l & 3) * 8;
    int rb = w * 32;
    const unsigned short* gA0 = Wb + (long long)(m0 + rb + srow) * K_DIM + ks + scol;
    const unsigned short* gA1 = gA0 + 16LL * K_DIM;
    const unsigned short* gB0 = XT + (long long)(n0 + rb + srow) * K_DIM + ks + scol;
    const unsigned short* gB1 = gB0 + 16LL * K_DIM;

    async16(gA0, &As[0][rb * BK]);
    async16(gA1, &As[0][(rb + 16) * BK]);
    async16(gB0, &Bs[0][rb * BK]);
    async16(gB1, &Bs[0][(rb + 16) * BK]);
    gA0 += BK; gA1 += BK; gB0 += BK; gB1 += BK;

    for (int kt = 0; kt < NIT; ++kt) {
        int cur = kt & 1;
        if (kt + 1 < NIT) {
            int nxt = cur ^ 1;
            async16(gA0, &As[nxt][rb * BK]);
            async16(gA1, &As[nxt][(rb + 16) * BK]);
            async16(gB0, &Bs[nxt][rb * BK]);
            async16(gB1, &Bs[nxt][(rb + 16) * BK]);
            gA0 += BK; gA1 += BK; gB0 += BK; gB1 += BK;
            WAIT_VM4();
        } else {
            WAIT_VM0();
        }
        RAW_BARRIER();

        bf16x8 a[8], b[4];
#pragma unroll
        for (int i = 0; i < 8; ++i)
            a[i] = *(const bf16x8*)&As[cur][(wm + i * 16 + lane16) * BK + quad * 8];
#pragma unroll
        for (int j = 0; j < 4; ++j)
            b[j] = *(const bf16x8*)&Bs[cur][(wn + j * 16 + lane16) * BK + quad * 8];

#pragma unroll
        for (int i = 0; i < 8; ++i)
#pragma unroll
            for (int j = 0; j < 4; ++j)
                acc[i][j] = __builtin_amdgcn_mfma_f32_16x16x32_bf16(a[i], b[j], acc[i][j], 0, 0, 0);

        if (kt + 1 < NIT)
            RAW_BARRIER();
    }

    // Epilogue: C/D layout col = lane&15, row = quad*4 + reg  [m89-verified]
#pragma unroll
    for (int j = 0; j < 4; ++j) {
        int n = n0 + wn + j * 16 + lane16;
        if (n >= N_REAL) continue;
#pragma unroll
        for (int i = 0; i < 8; ++i) {
            int mbase = m0 + wm + i * 16 + quad * 4;
#pragma unroll
            for (int r = 0; r < 4; ++r) {
                int m = mbase + r;
                if (m < M_REAL)
                    atomicAdd(&out[(long long)m * N_REAL + n], acc[i][j][r]);
            }
        }
    }
}

// ---------------------------------------------------------------------------
extern "C" void kernel_launch(void* const* d_in, const int* in_sizes, int n_in,
                              void* d_out, int out_size, void* d_ws, size_t ws_size,
                              hipStream_t stream) {
    const float* W    = (const float*)d_in[0];  // [2000][8192]
    const float* bias = (const float*)d_in[1];  // [2000]
    const float* X    = (const float*)d_in[2];  // [8192][2000]
    float* out = (float*)d_out;

    unsigned short* Wb = (unsigned short*)d_ws;                 // [2048][8192] bf16
    unsigned short* XT = Wb + (long long)M_PAD * K_DIM;         // [2048][8192] bf16

    prep_kernel<<<NB_CONVW + NB_CONVX + NB_INIT, 256, 0, stream>>>(W, X, bias, Wb, XT, out);

    gemm_kernel<<<(N_PAD / BN) * (M_PAD / BM) * SPLITK, 512, 0, stream>>>(Wb, XT, out);
}